// Round 12
// baseline (205.959 us; speedup 1.0000x reference)
//
#include <hip/hip_runtime.h>
#include <hip/hip_bf16.h>

// R12: attn reads K/V DIRECTLY from global (L2-resident; common-mistake #7) — no LDS,
// no barriers, K prefetched one subtile ahead (even/odd named register sets), V loaded
// just-in-time (hidden under QK+softmax). proj drops the now-unneeded K/V swizzles.
// PV in-register algebra + permlane transport unchanged (R10/R11-verified).

typedef __attribute__((ext_vector_type(4))) float f32x4;
typedef __attribute__((ext_vector_type(16))) float f32x16;
typedef __attribute__((ext_vector_type(8))) short bf16x8;
typedef __attribute__((ext_vector_type(4))) short bf16x4;
typedef __attribute__((ext_vector_type(2))) unsigned int u32x2;

static __device__ __forceinline__ unsigned short f2bf(float f) {
  union { float f; unsigned int u; } a; a.f = f;
  unsigned int u = a.u;
  u += 0x7FFFu + ((u >> 16) & 1u);   // RNE
  return (unsigned short)(u >> 16);
}

// pack two positive floats to bf16 pair (round-half-up) via v_perm_b32
static __device__ __forceinline__ unsigned pack2(float lo, float hi) {
  unsigned a = __float_as_uint(lo) + 0x8000u;
  unsigned b = __float_as_uint(hi) + 0x8000u;
  return __builtin_amdgcn_perm(b, a, 0x07060302);  // {b.hi16, a.hi16}
}

// lane[i] <-> lane[i^32] exchange, semantics-agnostic (verified R10/R11)
static __device__ __forceinline__ unsigned xchg32(unsigned x) {
  u32x2 r = __builtin_amdgcn_permlane32_swap(x, x, false, false);
  return x ^ r[0] ^ r[1];
}

#define AS1(p) ((const __attribute__((address_space(1))) void*)(p))
#define AS3(p) ((__attribute__((address_space(3))) void*)(p))

// ---------------- cvt: fp32 -> bf16 for 3 X inputs (4M each) + 4 weights (1M each) ----
__global__ __launch_bounds__(256) void cvt_kernel(
    const float* __restrict__ q, const float* __restrict__ k, const float* __restrict__ v,
    const float* __restrict__ wq, const float* __restrict__ wk, const float* __restrict__ wv,
    const float* __restrict__ wo, short* __restrict__ ws) {
  long i = (long)blockIdx.x * 256 + threadIdx.x;
  long e = i * 8;
  const float* src; long off;
  if (e < 12582912) {
    int s = (int)(e >> 22);
    src = s == 0 ? q : (s == 1 ? k : v);
    off = e & 4194303;
  } else {
    long e2 = e - 12582912;
    int s = (int)(e2 >> 20);
    src = s == 0 ? wq : (s == 1 ? wk : (s == 2 ? wv : wo));
    off = e2 & 1048575;
  }
  f32x4 a = *(const f32x4*)(src + off);
  f32x4 b = *(const f32x4*)(src + off + 4);
  bf16x8 o;
  o[0] = (short)f2bf(a[0]); o[1] = (short)f2bf(a[1]);
  o[2] = (short)f2bf(a[2]); o[3] = (short)f2bf(a[3]);
  o[4] = (short)f2bf(b[0]); o[5] = (short)f2bf(b[1]);
  o[6] = (short)f2bf(b[2]); o[7] = (short)f2bf(b[3]);
  *(bf16x8*)(ws + e) = o;
}

// ---------------- GEMM core: BK=64, swizzled LDS [128][64] (c ^= (row&7)*8) ----------
__device__ __forceinline__ void gemm_tile(const short* __restrict__ A, const short* __restrict__ B,
                                          int m0, int n0, f32x4 acc[4][4],
                                          short* As, short* Bs) {
  const int t = threadIdx.x;
  const int lane = t & 63, w = t >> 6;
  const int wr = w >> 1, wc = w & 1;
  const int x = lane & 15, g = lane >> 4;
  const int lr = lane >> 3;                 // row-within-chunk 0..7
  const int lc = ((lane & 7) ^ lr) * 8;     // inverse-swizzled source col (shorts)
  const int rswz = (x & 7) * 8;             // read-side swizzle (row&7 == x&7)

#pragma unroll
  for (int fm = 0; fm < 4; fm++)
#pragma unroll
    for (int fn = 0; fn < 4; fn++)
#pragma unroll
      for (int r = 0; r < 4; r++) acc[fm][fn][r] = 0.0f;

  for (int k0 = 0; k0 < 1024; k0 += 64) {
    __syncthreads();
#pragma unroll
    for (int i = 0; i < 4; i++) {
      int ch = w * 4 + i;                   // 0..15, 8 rows each
      const short* ga = A + (long)(m0 + ch * 8 + lr) * 1024 + k0 + lc;
      __builtin_amdgcn_global_load_lds(AS1(ga), AS3(As + ch * 512), 16, 0, 0);
      const short* gb = B + (long)(n0 + ch * 8 + lr) * 1024 + k0 + lc;
      __builtin_amdgcn_global_load_lds(AS1(gb), AS3(Bs + ch * 512), 16, 0, 0);
    }
    __syncthreads();
#pragma unroll
    for (int ks = 0; ks < 2; ks++) {
      bf16x8 af[4], bfv[4];
#pragma unroll
      for (int f = 0; f < 4; f++) {
        int c = (ks * 32 + g * 8) ^ rswz;
        af[f]  = *(const bf16x8*)(As + (wr * 64 + f * 16 + x) * 64 + c);
        bfv[f] = *(const bf16x8*)(Bs + (wc * 64 + f * 16 + x) * 64 + c);
      }
#pragma unroll
      for (int fm = 0; fm < 4; fm++)
#pragma unroll
        for (int fn = 0; fn < 4; fn++)
          acc[fm][fn] = __builtin_amdgcn_mfma_f32_16x16x32_bf16(af[fm], bfv[fn], acc[fm][fn], 0, 0, 0);
    }
  }
}

// ---------------- projections (plain K/V layouts — no swizzle) ----------------
__global__ __launch_bounds__(256) void proj_kernel(
    const short* __restrict__ Xq, const short* __restrict__ Xk, const short* __restrict__ Xv,
    const short* __restrict__ Wq, const short* __restrict__ Wk, const short* __restrict__ Wv,
    const float* __restrict__ bq, const float* __restrict__ bk, const float* __restrict__ bv,
    short* __restrict__ Qo, short* __restrict__ Ko, short* __restrict__ Vto) {
  __shared__ short As[8192], Bs[8192];
  const int z = blockIdx.z;
  const short* A = z == 0 ? Xq : (z == 1 ? Xk : Xv);
  const short* B = z == 0 ? Wq : (z == 1 ? Wk : Wv);
  const float* bias = z == 0 ? bq : (z == 1 ? bk : bv);
  const int m0 = blockIdx.y * 128, n0 = blockIdx.x * 128;
  f32x4 acc[4][4];
  gemm_tile(A, B, m0, n0, acc, As, Bs);

  const int lane = threadIdx.x & 63, w = threadIdx.x >> 6;
  const int wr = w >> 1, wc = w & 1, x = lane & 15, g = lane >> 4;

  if (z == 0) {
    const float scale = 0.04508422002778f;  // log2(e)/32
#pragma unroll
    for (int fn = 0; fn < 4; fn++) {
      int n = n0 + wc * 64 + fn * 16 + x;
      float bb = bias[n];
      int h = n >> 6, d = n & 63;
#pragma unroll
      for (int fm = 0; fm < 4; fm++) {
        int mb = m0 + wr * 64 + fm * 16 + g * 4;
#pragma unroll
        for (int r = 0; r < 4; r++) {
          int m = mb + r;
          int b = m >> 11, l = m & 2047;
          float val = (acc[fm][fn][r] + bb) * scale;
          Qo[((long)((b * 16 + h) * 2048 + l)) * 64 + d] = (short)f2bf(val);
        }
      }
    }
  } else if (z == 1) {
#pragma unroll
    for (int fn = 0; fn < 4; fn++) {
      int n = n0 + wc * 64 + fn * 16 + x;
      float bb = bias[n];
      int h = n >> 6, d = n & 63;
#pragma unroll
      for (int fm = 0; fm < 4; fm++) {
        int mb = m0 + wr * 64 + fm * 16 + g * 4;
#pragma unroll
        for (int r = 0; r < 4; r++) {
          int m = mb + r;
          int b = m >> 11, kv = m & 2047;
          Ko[((long)((b * 16 + h) * 2048 + kv)) * 64 + d] = (short)f2bf(acc[fm][fn][r] + bb);
        }
      }
    }
  } else {
#pragma unroll
    for (int fn = 0; fn < 4; fn++) {
      int n = n0 + wc * 64 + fn * 16 + x;
      float bb = bias[n];
      int h = n >> 6, d = n & 63;
#pragma unroll
      for (int fm = 0; fm < 4; fm++) {
        int mb = m0 + wr * 64 + fm * 16 + g * 4;
        int b = mb >> 11, kvb = mb & 2047;
        bf16x4 pk;
#pragma unroll
        for (int r = 0; r < 4; r++) pk[r] = (short)f2bf(acc[fm][fn][r] + bb);
        *(bf16x4*)(Vto + ((long)((b * 16 + h) * 64 + d)) * 2048 + kvb) = pk;
      }
    }
  }
}

// ---------------- flash attention: direct L2 reads, no LDS, no barriers ----------
__global__ __launch_bounds__(256, 2) void attn_kernel(
    const short* __restrict__ Qg, const short* __restrict__ Kg,
    const short* __restrict__ Vtg, short* __restrict__ Og) {
  const int t = threadIdx.x, w = t >> 6, lane = t & 63;
  const int col = lane & 31, hi = lane >> 5;
  const int bh = blockIdx.y;
  const int q0 = blockIdx.x * 128 + w * 32;
  const long hb = (long)bh * 2048 * 64;
  const short* Kb = Kg + hb;
  const short* Vb = Vtg + hb;   // [d 64][kv 2048]

  bf16x8 qf[4];
#pragma unroll
  for (int ksl = 0; ksl < 4; ksl++)
    qf[ksl] = *(const bf16x8*)(Qg + hb + (long)(q0 + col) * 64 + ksl * 16 + hi * 8);

  f32x16 o0, o1;
#pragma unroll
  for (int i = 0; i < 16; i++) { o0[i] = 0.0f; o1[i] = 0.0f; }
  float l_r = 0.0f;

  // load K fragments for subtile n (kv base n*64) into an 8-frag register set
  auto loadK = [&](int n, bf16x8 (&kf)[8]) {
    const long kvo = (long)(n & 31) * 64;
#pragma unroll
    for (int ksl = 0; ksl < 4; ksl++) {
      kf[ksl]     = *(const bf16x8*)(Kb + (kvo + col) * 64 + ksl * 16 + hi * 8);
      kf[4 + ksl] = *(const bf16x8*)(Kb + (kvo + col + 32) * 64 + ksl * 16 + hi * 8);
    }
  };

  // full subtile compute: V loaded just-in-time (hidden under QK + softmax)
  auto compute = [&](int n, bf16x8 (&kf)[8]) {
    const long kvo = (long)n * 64;
    bf16x8 vf[8];
#pragma unroll
    for (int KS = 0; KS < 4; KS++) {
      vf[KS]     = *(const bf16x8*)(Vb + (long)col * 2048 + kvo + KS * 16 + hi * 8);
      vf[4 + KS] = *(const bf16x8*)(Vb + (long)(col + 32) * 2048 + kvo + KS * 16 + hi * 8);
    }

    f32x16 s0, s1;
#pragma unroll
    for (int i = 0; i < 16; i++) { s0[i] = 0.0f; s1[i] = 0.0f; }
    __builtin_amdgcn_s_setprio(1);
#pragma unroll
    for (int ksl = 0; ksl < 4; ksl++) {
      s0 = __builtin_amdgcn_mfma_f32_32x32x16_bf16(kf[ksl], qf[ksl], s0, 0, 0, 0);
      s1 = __builtin_amdgcn_mfma_f32_32x32x16_bf16(kf[4 + ksl], qf[ksl], s1, 0, 0, 0);
    }
    __builtin_amdgcn_s_setprio(0);

    // fixed-max softmax: P = exp2(s); l accumulates lane-locally
#pragma unroll
    for (int i = 0; i < 16; i++) { s0[i] = __builtin_amdgcn_exp2f(s0[i]); }
#pragma unroll
    for (int i = 0; i < 16; i++) { s1[i] = __builtin_amdgcn_exp2f(s1[i]); }
    {
      float a0 = s0[0] + s0[1], a1 = s0[2] + s0[3], a2 = s0[4] + s0[5], a3 = s0[6] + s0[7];
      float a4 = s0[8] + s0[9], a5 = s0[10] + s0[11], a6 = s0[12] + s0[13], a7 = s0[14] + s0[15];
      float b0 = s1[0] + s1[1], b1 = s1[2] + s1[3], b2 = s1[4] + s1[5], b3 = s1[6] + s1[7];
      float b4 = s1[8] + s1[9], b5 = s1[10] + s1[11], b6 = s1[12] + s1[13], b7 = s1[14] + s1[15];
      float c0 = a0 + a1, c1 = a2 + a3, c2 = a4 + a5, c3 = a6 + a7;
      float c4 = b0 + b1, c5 = b2 + b3, c6 = b4 + b5, c7 = b6 + b7;
      float d0 = c0 + c1, d1 = c2 + c3, d2 = c4 + c5, d3 = c6 + c7;
      l_r += (d0 + d1) + (d2 + d3);
    }

    // O^T += Vt @ P^T ; in-register P, static indices (rule #20), verified algebra
#define PVSTEP(SEL, KS)                                                       \
    {                                                                         \
      unsigned pkA0 = pack2(SEL[8 * ((KS) & 1) + 0], SEL[8 * ((KS) & 1) + 1]); \
      unsigned pkA1 = pack2(SEL[8 * ((KS) & 1) + 2], SEL[8 * ((KS) & 1) + 3]); \
      unsigned pkB0 = pack2(SEL[8 * ((KS) & 1) + 4], SEL[8 * ((KS) & 1) + 5]); \
      unsigned pkB1 = pack2(SEL[8 * ((KS) & 1) + 6], SEL[8 * ((KS) & 1) + 7]); \
      unsigned own0 = hi ? pkB0 : pkA0, own1 = hi ? pkB1 : pkA1;              \
      unsigned oth0 = hi ? pkA0 : pkB0, oth1 = hi ? pkA1 : pkB1;              \
      unsigned r0 = xchg32(oth0);                                             \
      unsigned r1 = xchg32(oth1);                                             \
      union { unsigned u[4]; bf16x8 v; } pb;                                  \
      pb.u[0] = hi ? r0 : own0; pb.u[1] = hi ? r1 : own1;                     \
      pb.u[2] = hi ? own0 : r0; pb.u[3] = hi ? own1 : r1;                     \
      __builtin_amdgcn_s_setprio(1);                                          \
      o0 = __builtin_amdgcn_mfma_f32_32x32x16_bf16(vf[KS], pb.v, o0, 0, 0, 0);     \
      o1 = __builtin_amdgcn_mfma_f32_32x32x16_bf16(vf[4 + KS], pb.v, o1, 0, 0, 0); \
      __builtin_amdgcn_s_setprio(0);                                          \
    }
    PVSTEP(s0, 0)
    PVSTEP(s0, 1)
    PVSTEP(s1, 2)
    PVSTEP(s1, 3)
#undef PVSTEP
  };

  bf16x8 kA[8], kB[8];
  loadK(0, kA);
  for (int n = 0; n < 32; n += 2) {
    loadK(n + 1, kB);     // prefetch next subtile's K
    compute(n, kA);
    loadK(n + 2, kA);     // (n=30: wraps to tile 0, harmless)
    compute(n + 1, kB);
  }

  // epilogue
  const float l_tot = l_r + __uint_as_float(xchg32(__float_as_uint(l_r)));
  const float inv = 1.0f / l_tot;
  const int b = bh >> 4, h = bh & 15;
  const long base = ((long)(b * 2048 + q0 + col) * 16 + h) * 64;
#pragma unroll
  for (int dh = 0; dh < 2; dh++) {
#pragma unroll
    for (int g2 = 0; g2 < 4; g2++) {
      float x0 = (dh ? o1[g2 * 4 + 0] : o0[g2 * 4 + 0]) * inv;
      float x1 = (dh ? o1[g2 * 4 + 1] : o0[g2 * 4 + 1]) * inv;
      float x2 = (dh ? o1[g2 * 4 + 2] : o0[g2 * 4 + 2]) * inv;
      float x3 = (dh ? o1[g2 * 4 + 3] : o0[g2 * 4 + 3]) * inv;
      u32x2 rr;
      rr[0] = (unsigned)f2bf(x0) | ((unsigned)f2bf(x1) << 16);
      rr[1] = (unsigned)f2bf(x2) | ((unsigned)f2bf(x3) << 16);
      int d = dh * 32 + g2 * 8 + hi * 4;
      *(u32x2*)(Og + base + d) = rr;
    }
  }
}

// ---------------- output projection ----------------
__global__ __launch_bounds__(256) void out_kernel(
    const short* __restrict__ O, const short* __restrict__ Wo,
    const float* __restrict__ bo, float* __restrict__ out) {
  __shared__ short As[8192], Bs[8192];
  const int m0 = blockIdx.y * 128, n0 = blockIdx.x * 128;
  f32x4 acc[4][4];
  gemm_tile(O, Wo, m0, n0, acc, As, Bs);
  const int lane = threadIdx.x & 63, w = threadIdx.x >> 6;
  const int wr = w >> 1, wc = w & 1, x = lane & 15, g = lane >> 4;
#pragma unroll
  for (int fn = 0; fn < 4; fn++) {
    int n = n0 + wc * 64 + fn * 16 + x;
    float bb = bo[n];
#pragma unroll
    for (int fm = 0; fm < 4; fm++) {
      int mb = m0 + wr * 64 + fm * 16 + g * 4;
#pragma unroll
      for (int r = 0; r < 4; r++)
        out[(long)(mb + r) * 1024 + n] = acc[fm][fn][r] + bb;
    }
  }
}

extern "C" void kernel_launch(void* const* d_in, const int* in_sizes, int n_in,
                              void* d_out, int out_size, void* d_ws, size_t ws_size,
                              hipStream_t stream) {
  const float* q  = (const float*)d_in[0];
  const float* k  = (const float*)d_in[1];
  const float* v  = (const float*)d_in[2];
  const float* wq = (const float*)d_in[3];
  const float* bq = (const float*)d_in[4];
  const float* wk = (const float*)d_in[5];
  const float* bk = (const float*)d_in[6];
  const float* wv = (const float*)d_in[7];
  const float* bv = (const float*)d_in[8];
  const float* wo = (const float*)d_in[9];
  const float* bo = (const float*)d_in[10];

  short* ws  = (short*)d_ws;
  short* Xq  = ws;
  short* Xk  = Xq + 4194304;
  short* Xv  = Xk + 4194304;
  short* Wqb = Xv + 4194304;
  short* Wkb = Wqb + 1048576;
  short* Wvb = Wkb + 1048576;
  short* Wob = Wvb + 1048576;
  short* Qb  = Wob + 1048576;
  short* Kb  = Qb + 4194304;
  short* Vtb = Kb + 4194304;
  short* Ob  = Vtb + 4194304;

  cvt_kernel<<<8192, 256, 0, stream>>>(q, k, v, wq, wk, wv, wo, ws);
  dim3 gp(8, 32, 3);
  proj_kernel<<<gp, 256, 0, stream>>>(Xq, Xk, Xv, Wqb, Wkb, Wvb, bq, bk, bv, Qb, Kb, Vtb);
  dim3 ga(16, 32);
  attn_kernel<<<ga, 256, 0, stream>>>(Qb, Kb, Vtb, Ob);
  dim3 gf(8, 32);
  out_kernel<<<gf, 256, 0, stream>>>(Ob, Wob, bo, (float*)d_out);
}

// Round 13
// 130.302 us; speedup vs baseline: 1.5806x; 1.5806x over previous
//
#include <hip/hip_runtime.h>
#include <hip/hip_bf16.h>

// R13: revert R12 (direct-global reads were uncoalesced scatter — 64 cache lines per
// wave-load). Base = R11 (passed, attn 57.2us). ONE new lever: XCD-chunked block remap
// (T1) in attn/proj/out so each XCD's private L2 keeps its working set:
// attn: 4 whole heads per XCD (K+V = 4MB = L2 size) -> kills the 4x K/V HBM refetch.

typedef __attribute__((ext_vector_type(4))) float f32x4;
typedef __attribute__((ext_vector_type(16))) float f32x16;
typedef __attribute__((ext_vector_type(8))) short bf16x8;
typedef __attribute__((ext_vector_type(4))) short bf16x4;
typedef __attribute__((ext_vector_type(2))) unsigned int u32x2;

static __device__ __forceinline__ unsigned short f2bf(float f) {
  union { float f; unsigned int u; } a; a.f = f;
  unsigned int u = a.u;
  u += 0x7FFFu + ((u >> 16) & 1u);   // RNE
  return (unsigned short)(u >> 16);
}

// pack two positive floats to bf16 pair (round-half-up) via v_perm_b32
static __device__ __forceinline__ unsigned pack2(float lo, float hi) {
  unsigned a = __float_as_uint(lo) + 0x8000u;
  unsigned b = __float_as_uint(hi) + 0x8000u;
  return __builtin_amdgcn_perm(b, a, 0x07060302);  // {b.hi16, a.hi16}
}

// lane[i] <-> lane[i^32] exchange, semantics-agnostic (verified R10/R11)
static __device__ __forceinline__ unsigned xchg32(unsigned x) {
  u32x2 r = __builtin_amdgcn_permlane32_swap(x, x, false, false);
  return x ^ r[0] ^ r[1];
}

#define AS1(p) ((const __attribute__((address_space(1))) void*)(p))
#define AS3(p) ((__attribute__((address_space(3))) void*)(p))

// ---------------- cvt: fp32 -> bf16 for 3 X inputs (4M each) + 4 weights (1M each) ----
__global__ __launch_bounds__(256) void cvt_kernel(
    const float* __restrict__ q, const float* __restrict__ k, const float* __restrict__ v,
    const float* __restrict__ wq, const float* __restrict__ wk, const float* __restrict__ wv,
    const float* __restrict__ wo, short* __restrict__ ws) {
  long i = (long)blockIdx.x * 256 + threadIdx.x;
  long e = i * 8;
  const float* src; long off;
  if (e < 12582912) {
    int s = (int)(e >> 22);
    src = s == 0 ? q : (s == 1 ? k : v);
    off = e & 4194303;
  } else {
    long e2 = e - 12582912;
    int s = (int)(e2 >> 20);
    src = s == 0 ? wq : (s == 1 ? wk : (s == 2 ? wv : wo));
    off = e2 & 1048575;
  }
  f32x4 a = *(const f32x4*)(src + off);
  f32x4 b = *(const f32x4*)(src + off + 4);
  bf16x8 o;
  o[0] = (short)f2bf(a[0]); o[1] = (short)f2bf(a[1]);
  o[2] = (short)f2bf(a[2]); o[3] = (short)f2bf(a[3]);
  o[4] = (short)f2bf(b[0]); o[5] = (short)f2bf(b[1]);
  o[6] = (short)f2bf(b[2]); o[7] = (short)f2bf(b[3]);
  *(bf16x8*)(ws + e) = o;
}

// ---------------- GEMM core: BK=64, swizzled LDS [128][64] (c ^= (row&7)*8) ----------
__device__ __forceinline__ void gemm_tile(const short* __restrict__ A, const short* __restrict__ B,
                                          int m0, int n0, f32x4 acc[4][4],
                                          short* As, short* Bs) {
  const int t = threadIdx.x;
  const int lane = t & 63, w = t >> 6;
  const int wr = w >> 1, wc = w & 1;
  const int x = lane & 15, g = lane >> 4;
  const int lr = lane >> 3;                 // row-within-chunk 0..7
  const int lc = ((lane & 7) ^ lr) * 8;     // inverse-swizzled source col (shorts)
  const int rswz = (x & 7) * 8;             // read-side swizzle (row&7 == x&7)

#pragma unroll
  for (int fm = 0; fm < 4; fm++)
#pragma unroll
    for (int fn = 0; fn < 4; fn++)
#pragma unroll
      for (int r = 0; r < 4; r++) acc[fm][fn][r] = 0.0f;

  for (int k0 = 0; k0 < 1024; k0 += 64) {
    __syncthreads();
#pragma unroll
    for (int i = 0; i < 4; i++) {
      int ch = w * 4 + i;                   // 0..15, 8 rows each
      const short* ga = A + (long)(m0 + ch * 8 + lr) * 1024 + k0 + lc;
      __builtin_amdgcn_global_load_lds(AS1(ga), AS3(As + ch * 512), 16, 0, 0);
      const short* gb = B + (long)(n0 + ch * 8 + lr) * 1024 + k0 + lc;
      __builtin_amdgcn_global_load_lds(AS1(gb), AS3(Bs + ch * 512), 16, 0, 0);
    }
    __syncthreads();
#pragma unroll
    for (int ks = 0; ks < 2; ks++) {
      bf16x8 af[4], bfv[4];
#pragma unroll
      for (int f = 0; f < 4; f++) {
        int c = (ks * 32 + g * 8) ^ rswz;
        af[f]  = *(const bf16x8*)(As + (wr * 64 + f * 16 + x) * 64 + c);
        bfv[f] = *(const bf16x8*)(Bs + (wc * 64 + f * 16 + x) * 64 + c);
      }
#pragma unroll
      for (int fm = 0; fm < 4; fm++)
#pragma unroll
        for (int fn = 0; fn < 4; fn++)
          acc[fm][fn] = __builtin_amdgcn_mfma_f32_16x16x32_bf16(af[fm], bfv[fn], acc[fm][fn], 0, 0, 0);
    }
  }
}

// ---------------- projections (XCD-chunked remap) ----------------
__global__ __launch_bounds__(256) void proj_kernel(
    const short* __restrict__ Xq, const short* __restrict__ Xk, const short* __restrict__ Xv,
    const short* __restrict__ Wq, const short* __restrict__ Wk, const short* __restrict__ Wv,
    const float* __restrict__ bq, const float* __restrict__ bk, const float* __restrict__ bv,
    short* __restrict__ Qo, short* __restrict__ Ko, short* __restrict__ Vto) {
  __shared__ short As[8192], Bs[8192];
  // bijective XCD-chunk remap: nwg=768, 96 consecutive wgids per XCD
  const int lin = blockIdx.z * 256 + blockIdx.y * 8 + blockIdx.x;
  const int wgid = (lin & 7) * 96 + (lin >> 3);
  const int z = wgid >> 8;
  const int m0 = ((wgid >> 3) & 31) * 128, n0 = (wgid & 7) * 128;
  const short* A = z == 0 ? Xq : (z == 1 ? Xk : Xv);
  const short* B = z == 0 ? Wq : (z == 1 ? Wk : Wv);
  const float* bias = z == 0 ? bq : (z == 1 ? bk : bv);
  f32x4 acc[4][4];
  gemm_tile(A, B, m0, n0, acc, As, Bs);

  const int lane = threadIdx.x & 63, w = threadIdx.x >> 6;
  const int wr = w >> 1, wc = w & 1, x = lane & 15, g = lane >> 4;

  if (z == 0) {
    const float scale = 0.04508422002778f;  // log2(e)/32
#pragma unroll
    for (int fn = 0; fn < 4; fn++) {
      int n = n0 + wc * 64 + fn * 16 + x;
      float bb = bias[n];
      int h = n >> 6, d = n & 63;
#pragma unroll
      for (int fm = 0; fm < 4; fm++) {
        int mb = m0 + wr * 64 + fm * 16 + g * 4;
#pragma unroll
        for (int r = 0; r < 4; r++) {
          int m = mb + r;
          int b = m >> 11, l = m & 2047;
          float val = (acc[fm][fn][r] + bb) * scale;
          Qo[((long)((b * 16 + h) * 2048 + l)) * 64 + d] = (short)f2bf(val);
        }
      }
    }
  } else if (z == 1) {
#pragma unroll
    for (int fn = 0; fn < 4; fn++) {
      int n = n0 + wc * 64 + fn * 16 + x;
      float bb = bias[n];
      int h = n >> 6, d = n & 63;
#pragma unroll
      for (int fm = 0; fm < 4; fm++) {
        int mb = m0 + wr * 64 + fm * 16 + g * 4;
#pragma unroll
        for (int r = 0; r < 4; r++) {
          int m = mb + r;
          int b = m >> 11, kv = m & 2047;
          int ds = d ^ ((kv & 7) << 3);
          Ko[((long)((b * 16 + h) * 2048 + kv)) * 64 + ds] = (short)f2bf(acc[fm][fn][r] + bb);
        }
      }
    }
  } else {
#pragma unroll
    for (int fn = 0; fn < 4; fn++) {
      int n = n0 + wc * 64 + fn * 16 + x;
      float bb = bias[n];
      int h = n >> 6, d = n & 63;
#pragma unroll
      for (int fm = 0; fm < 4; fm++) {
        int mb = m0 + wr * 64 + fm * 16 + g * 4;
        int b = mb >> 11, kvb = mb & 2047;
        bf16x4 pk;
#pragma unroll
        for (int r = 0; r < 4; r++) pk[r] = (short)f2bf(acc[fm][fn][r] + bb);
        int kvs = (kvb & ~63) | ((kvb & 63) ^ ((d & 7) << 3));
        *(bf16x4*)(Vto + ((long)((b * 16 + h) * 64 + d)) * 2048 + kvs) = pk;
      }
    }
  }
}

// ---------------- flash attention: R11 body + XCD-chunked remap (4 heads/XCD) --------
__global__ __launch_bounds__(256, 2) void attn_kernel(
    const short* __restrict__ Qg, const short* __restrict__ Kg,
    const short* __restrict__ Vtg, short* __restrict__ Og) {
  __shared__ __align__(16) short Kl[2][8192];   // [kv 128][d64 ^ ((kv&7)*8)]
  __shared__ __align__(16) short Vl[2][8192];   // [d 64][kv128; per-64 ^ ((d&7)*8)]
  const int t = threadIdx.x, w = t >> 6, lane = t & 63;
  const int col = lane & 31, hi = lane >> 5;
  // bijective XCD-chunk remap: nwg=512 -> 64 per XCD -> bh in [4*xcd, 4*xcd+4)
  const int lin = blockIdx.y * 16 + blockIdx.x;
  const int wgid = (lin & 7) * 64 + (lin >> 3);
  const int bh = wgid >> 4;
  const int q0 = (wgid & 15) * 128 + w * 32;
  const long hb = (long)bh * 2048 * 64;
  const int swz = (col & 7) * 8;

  bf16x8 qf[4];
#pragma unroll
  for (int ksl = 0; ksl < 4; ksl++)
    qf[ksl] = *(const bf16x8*)(Qg + hb + (long)(q0 + col) * 64 + ksl * 16 + hi * 8);

  f32x16 o0, o1;
#pragma unroll
  for (int i = 0; i < 16; i++) { o0[i] = 0.0f; o1[i] = 0.0f; }
  float l_r = 0.0f;

  auto stage = [&](int buf, int kv0) {
#pragma unroll
    for (int it = 0; it < 4; it++) {
      int cb = it * 256 + w * 64;
      const short* gk = Kg + hb + (long)kv0 * 64 + (cb + lane) * 8;   // [128][64] tile
      __builtin_amdgcn_global_load_lds(AS1(gk), AS3(&Kl[buf][cb * 8]), 16, 0, 0);
      int c = cb + lane;
      const short* gv = Vtg + hb + (long)(c >> 4) * 2048 + kv0 + (c & 15) * 8;  // [64][128]
      __builtin_amdgcn_global_load_lds(AS1(gv), AS3(&Vl[buf][cb * 8]), 16, 0, 0);
    }
  };

  stage(0, 0);
  __syncthreads();

  for (int ti = 0; ti < 16; ti++) {
    const int buf = ti & 1;
    if (ti < 15) stage(buf ^ 1, (ti + 1) * 128);

#pragma unroll
    for (int st = 0; st < 2; st++) {
      // S^T = K @ Q^T for kv sub-tile [st*64, st*64+64)
      f32x16 s0, s1;
#pragma unroll
      for (int i = 0; i < 16; i++) { s0[i] = 0.0f; s1[i] = 0.0f; }
      __builtin_amdgcn_s_setprio(1);
#pragma unroll
      for (int ksl = 0; ksl < 4; ksl++) {
        int dcol = (ksl * 16 + hi * 8) ^ swz;
        bf16x8 a0 = *(const bf16x8*)(&Kl[buf][(st * 64 + col) * 64 + dcol]);
        bf16x8 a1 = *(const bf16x8*)(&Kl[buf][(st * 64 + col + 32) * 64 + dcol]);
        s0 = __builtin_amdgcn_mfma_f32_32x32x16_bf16(a0, qf[ksl], s0, 0, 0, 0);
        s1 = __builtin_amdgcn_mfma_f32_32x32x16_bf16(a1, qf[ksl], s1, 0, 0, 0);
      }
      __builtin_amdgcn_s_setprio(0);

      // fixed-max softmax: P = exp2(s); l accumulates lane-locally
#pragma unroll
      for (int i = 0; i < 16; i++) { s0[i] = __builtin_amdgcn_exp2f(s0[i]); }
#pragma unroll
      for (int i = 0; i < 16; i++) { s1[i] = __builtin_amdgcn_exp2f(s1[i]); }
      {
        float a0 = s0[0] + s0[1], a1 = s0[2] + s0[3], a2 = s0[4] + s0[5], a3 = s0[6] + s0[7];
        float a4 = s0[8] + s0[9], a5 = s0[10] + s0[11], a6 = s0[12] + s0[13], a7 = s0[14] + s0[15];
        float b0 = s1[0] + s1[1], b1 = s1[2] + s1[3], b2 = s1[4] + s1[5], b3 = s1[6] + s1[7];
        float b4 = s1[8] + s1[9], b5 = s1[10] + s1[11], b6 = s1[12] + s1[13], b7 = s1[14] + s1[15];
        float c0 = a0 + a1, c1 = a2 + a3, c2 = a4 + a5, c3 = a6 + a7;
        float c4 = b0 + b1, c5 = b2 + b3, c6 = b4 + b5, c7 = b6 + b7;
        float d0 = c0 + c1, d1 = c2 + c3, d2 = c4 + c5, d3 = c6 + c7;
        l_r += (d0 + d1) + (d2 + d3);
      }

      // O^T += Vt @ P^T ; in-register P, static indices (rule #20), verified algebra
#define PVSTEP(SEL, KS)                                                       \
      {                                                                       \
        unsigned pkA0 = pack2(SEL[8 * ((KS) & 1) + 0], SEL[8 * ((KS) & 1) + 1]); \
        unsigned pkA1 = pack2(SEL[8 * ((KS) & 1) + 2], SEL[8 * ((KS) & 1) + 3]); \
        unsigned pkB0 = pack2(SEL[8 * ((KS) & 1) + 4], SEL[8 * ((KS) & 1) + 5]); \
        unsigned pkB1 = pack2(SEL[8 * ((KS) & 1) + 6], SEL[8 * ((KS) & 1) + 7]); \
        unsigned own0 = hi ? pkB0 : pkA0, own1 = hi ? pkB1 : pkA1;            \
        unsigned oth0 = hi ? pkA0 : pkB0, oth1 = hi ? pkA1 : pkB1;            \
        unsigned r0 = xchg32(oth0);                                           \
        unsigned r1 = xchg32(oth1);                                           \
        union { unsigned u[4]; bf16x8 v; } pb;                                \
        pb.u[0] = hi ? r0 : own0; pb.u[1] = hi ? r1 : own1;                   \
        pb.u[2] = hi ? own0 : r0; pb.u[3] = hi ? own1 : r1;                   \
        const int vcol = ((KS) * 16 + hi * 8) ^ swz;                          \
        bf16x8 vb0 = *(const bf16x8*)(&Vl[buf][col * 128 + st * 64 + vcol]);  \
        bf16x8 vb1 = *(const bf16x8*)(&Vl[buf][(col + 32) * 128 + st * 64 + vcol]); \
        __builtin_amdgcn_s_setprio(1);                                        \
        o0 = __builtin_amdgcn_mfma_f32_32x32x16_bf16(vb0, pb.v, o0, 0, 0, 0); \
        o1 = __builtin_amdgcn_mfma_f32_32x32x16_bf16(vb1, pb.v, o1, 0, 0, 0); \
        __builtin_amdgcn_s_setprio(0);                                        \
      }
      PVSTEP(s0, 0)
      PVSTEP(s0, 1)
      PVSTEP(s1, 2)
      PVSTEP(s1, 3)
#undef PVSTEP
    }

    __syncthreads();
  }

  // epilogue
  const float l_tot = l_r + __uint_as_float(xchg32(__float_as_uint(l_r)));
  const float inv = 1.0f / l_tot;
  const int b = bh >> 4, h = bh & 15;
  const long base = ((long)(b * 2048 + q0 + col) * 16 + h) * 64;
#pragma unroll
  for (int dh = 0; dh < 2; dh++) {
#pragma unroll
    for (int g2 = 0; g2 < 4; g2++) {
      float x0 = (dh ? o1[g2 * 4 + 0] : o0[g2 * 4 + 0]) * inv;
      float x1 = (dh ? o1[g2 * 4 + 1] : o0[g2 * 4 + 1]) * inv;
      float x2 = (dh ? o1[g2 * 4 + 2] : o0[g2 * 4 + 2]) * inv;
      float x3 = (dh ? o1[g2 * 4 + 3] : o0[g2 * 4 + 3]) * inv;
      u32x2 rr;
      rr[0] = (unsigned)f2bf(x0) | ((unsigned)f2bf(x1) << 16);
      rr[1] = (unsigned)f2bf(x2) | ((unsigned)f2bf(x3) << 16);
      int d = dh * 32 + g2 * 8 + hi * 4;
      *(u32x2*)(Og + base + d) = rr;
    }
  }
}

// ---------------- output projection (XCD-chunked remap) ----------------
__global__ __launch_bounds__(256) void out_kernel(
    const short* __restrict__ O, const short* __restrict__ Wo,
    const float* __restrict__ bo, float* __restrict__ out) {
  __shared__ short As[8192], Bs[8192];
  const int lin = blockIdx.y * 8 + blockIdx.x;
  const int wgid = (lin & 7) * 32 + (lin >> 3);
  const int m0 = (wgid >> 3) * 128, n0 = (wgid & 7) * 128;
  f32x4 acc[4][4];
  gemm_tile(O, Wo, m0, n0, acc, As, Bs);
  const int lane = threadIdx.x & 63, w = threadIdx.x >> 6;
  const int wr = w >> 1, wc = w & 1, x = lane & 15, g = lane >> 4;
#pragma unroll
  for (int fn = 0; fn < 4; fn++) {
    int n = n0 + wc * 64 + fn * 16 + x;
    float bb = bo[n];
#pragma unroll
    for (int fm = 0; fm < 4; fm++) {
      int mb = m0 + wr * 64 + fm * 16 + g * 4;
#pragma unroll
      for (int r = 0; r < 4; r++)
        out[(long)(mb + r) * 1024 + n] = acc[fm][fn][r] + bb;
    }
  }
}

extern "C" void kernel_launch(void* const* d_in, const int* in_sizes, int n_in,
                              void* d_out, int out_size, void* d_ws, size_t ws_size,
                              hipStream_t stream) {
  const float* q  = (const float*)d_in[0];
  const float* k  = (const float*)d_in[1];
  const float* v  = (const float*)d_in[2];
  const float* wq = (const float*)d_in[3];
  const float* bq = (const float*)d_in[4];
  const float* wk = (const float*)d_in[5];
  const float* bk = (const float*)d_in[6];
  const float* wv = (const float*)d_in[7];
  const float* bv = (const float*)d_in[8];
  const float* wo = (const float*)d_in[9];
  const float* bo = (const float*)d_in[10];

  short* ws  = (short*)d_ws;
  short* Xq  = ws;
  short* Xk  = Xq + 4194304;
  short* Xv  = Xk + 4194304;
  short* Wqb = Xv + 4194304;
  short* Wkb = Wqb + 1048576;
  short* Wvb = Wkb + 1048576;
  short* Wob = Wvb + 1048576;
  short* Qb  = Wob + 1048576;
  short* Kb  = Qb + 4194304;
  short* Vtb = Kb + 4194304;
  short* Ob  = Vtb + 4194304;

  cvt_kernel<<<8192, 256, 0, stream>>>(q, k, v, wq, wk, wv, wo, ws);
  dim3 gp(8, 32, 3);
  proj_kernel<<<gp, 256, 0, stream>>>(Xq, Xk, Xv, Wqb, Wkb, Wvb, bq, bk, bv, Qb, Kb, Vtb);
  dim3 ga(16, 32);
  attn_kernel<<<ga, 256, 0, stream>>>(Qb, Kb, Vtb, Ob);
  dim3 gf(8, 32);
  out_kernel<<<gf, 256, 0, stream>>>(Ob, Wob, bo, (float*)d_out);
}